// Round 2
// baseline (2662.548 us; speedup 1.0000x reference)
//
#include <hip/hip_runtime.h>
#include <hip/hip_bf16.h>

#define BB 8
#define CC 64
#define NN 4096
#define KK 20
#define OO 64
#define NCAND 32         // kNN candidate list size (top-20 needed; 12 guard ranks vs bf16 noise)
#define FMAXV 3.402823466e38f

typedef __attribute__((ext_vector_type(8))) short short8;   // 8 bf16 = 4 VGPRs (MFMA A/B frag)
typedef __attribute__((ext_vector_type(4))) float f32x4;    // MFMA C/D frag

// ---------------------------------------------------------------------------
// Kernel T: transpose x (B,C,N) -> xt (B,N,C) f32 + xb (B,N,C) bf16; sq[n]=sum x^2
// ---------------------------------------------------------------------------
__global__ __launch_bounds__(256) void ktrans(const float* __restrict__ x,
                                              float* __restrict__ xt,
                                              unsigned short* __restrict__ xb,
                                              float* __restrict__ sq) {
  __shared__ float tile[64][65];
  const int b = blockIdx.y, n0 = blockIdx.x * 64;
  const int lane = threadIdx.x & 63, grp = threadIdx.x >> 6;
  #pragma unroll
  for (int j = 0; j < 16; ++j) {
    int c = grp + j * 4;
    tile[c][lane] = x[((size_t)b * CC + c) * NN + n0 + lane];
  }
  __syncthreads();
  #pragma unroll
  for (int j = 0; j < 16; ++j) {
    int n = grp + j * 4;
    float vv = tile[lane][n];
    size_t off = ((size_t)b * NN + n0 + n) * CC + lane;
    xt[off] = vv;
    unsigned int u = __builtin_bit_cast(unsigned int, vv);
    xb[off] = (unsigned short)((u + 0x7FFFu + ((u >> 16) & 1u)) >> 16);  // RNE bf16
  }
  if (threadIdx.x < 64) {
    float s = 0.f;
    #pragma unroll
    for (int c = 0; c < 64; ++c) { float vv = tile[c][lane]; s += vv * vv; }
    sq[(size_t)b * NN + lane + n0] = s;
  }
}

// ---------------------------------------------------------------------------
// Wave-parallel top-NCAND insertion; list in lanes 0..31. th = stale-high bound.
// Keeps the NCAND smallest by (d, m) lexicographic; candidates arrive m-increasing.
// ---------------------------------------------------------------------------
__device__ __forceinline__ void insert32(float& lv, int& lm, float& th,
                                         float dcand, int mcand, int lane) {
  unsigned long long bal = __ballot(dcand < th);
  while (bal) {
    int src = __ffsll(bal) - 1;
    bal &= bal - 1;
    float dc = __shfl(dcand, src);
    int   mc = __shfl(mcand, src);
    float v  = (lane < NCAND) ? lv : -FMAXV;
    int   mm = (lane < NCAND) ? lm : -2000000;
    int  pos = lane;
    #pragma unroll
    for (int off = 32; off >= 1; off >>= 1) {
      float v2 = __shfl_xor(v, off);
      int  mm2 = __shfl_xor(mm, off);
      int   p2 = __shfl_xor(pos, off);
      bool take = (v2 > v) || (v2 == v && mm2 > mm);
      if (take) { v = v2; mm = mm2; pos = p2; }
    }
    if (dc >= v) continue;          // exact re-check vs true current max
    if (lane == pos) { lv = dc; lm = mc; }
    th = v;                         // stale-but-safe
  }
}

// ---------------------------------------------------------------------------
// Kernel KNN2: bf16-MFMA gram + streaming top-32 + exact f32 refine -> top-20.
// Block: 32 rows, 4 waves; per iter each wave computes a 32x32 MFMA sub-tile of
// the 32x128 distance tile; scan phase partitions 8 rows/wave over full tile.
// ---------------------------------------------------------------------------
__global__ __launch_bounds__(256) void kknn2(const unsigned short* __restrict__ xb,
                                             const float* __restrict__ xt,
                                             const float* __restrict__ sq,
                                             int* __restrict__ knn) {
  __shared__ float sd[32][130];   // stride 130: 2*row+col banks -> 2-way (free)
  __shared__ float ssq[128];
  const int b = blockIdx.y;
  const int n0 = blockIdx.x * 32;
  const int lane = threadIdx.x & 63, w = threadIdx.x >> 6;
  const int l15 = lane & 15, q = lane >> 4;

  const unsigned short* xbB = xb + (size_t)b * NN * CC;

  // A frags (held for whole block): A[m = l15][k = q*8 + j], rt row-tile, ks K-step
  short8 afr[2][2];
  #pragma unroll
  for (int rt = 0; rt < 2; ++rt)
    #pragma unroll
    for (int ks = 0; ks < 2; ++ks) {
      const unsigned short* p = xbB + (size_t)(n0 + rt * 16 + l15) * CC + ks * 32 + q * 8;
      afr[rt][ks] = __builtin_bit_cast(short8, *(const int4*)p);
    }

  float lv[8], th[8];
  int   lm[8];
  #pragma unroll
  for (int r = 0; r < 8; ++r) { lv[r] = FMAXV; th[r] = FMAXV; lm[r] = -1 - lane; }

  for (int t = 0; t < NN / 128; ++t) {
    const int c0 = t * 128;
    if (threadIdx.x < 128) ssq[threadIdx.x] = sq[(size_t)b * NN + c0 + threadIdx.x];

    short8 bfr[2][2];
    #pragma unroll
    for (int ct = 0; ct < 2; ++ct)
      #pragma unroll
      for (int ks = 0; ks < 2; ++ks) {
        const unsigned short* p = xbB + (size_t)(c0 + w * 32 + ct * 16 + l15) * CC + ks * 32 + q * 8;
        bfr[ct][ks] = __builtin_bit_cast(short8, *(const int4*)p);
      }
    f32x4 acc[2][2];
    #pragma unroll
    for (int rt = 0; rt < 2; ++rt)
      #pragma unroll
      for (int ct = 0; ct < 2; ++ct) {
        acc[rt][ct] = (f32x4){0.f, 0.f, 0.f, 0.f};
        acc[rt][ct] = __builtin_amdgcn_mfma_f32_16x16x32_bf16(afr[rt][0], bfr[ct][0], acc[rt][ct], 0, 0, 0);
        acc[rt][ct] = __builtin_amdgcn_mfma_f32_16x16x32_bf16(afr[rt][1], bfr[ct][1], acc[rt][ct], 0, 0, 0);
      }

    __syncthreads();   // ssq staged; previous scan done reading sd
    // epilogue: d = sq[col] - 2*dot  (row-constant sq[row] dropped; rank-invariant)
    #pragma unroll
    for (int rt = 0; rt < 2; ++rt)
      #pragma unroll
      for (int ct = 0; ct < 2; ++ct) {
        const int cl = w * 32 + ct * 16 + l15;      // col within 128-tile
        #pragma unroll
        for (int j = 0; j < 4; ++j) {
          const int rl = rt * 16 + q * 4 + j;       // row within 32-block
          float d = ssq[cl] - 2.f * acc[rt][ct][j];
          if (c0 + cl == n0 + rl) d = FMAXV;        // exclude self
          sd[rl][cl] = d;
        }
      }
    __syncthreads();   // sd visible

    // scan: wave w owns rows w*8 .. w*8+7
    #pragma unroll
    for (int r = 0; r < 8; ++r) {
      const int rl = w * 8 + r;
      float d0 = sd[rl][lane];
      float d1 = sd[rl][64 + lane];
      insert32(lv[r], lm[r], th[r], d0, c0 + lane, lane);
      insert32(lv[r], lm[r], th[r], d1, c0 + 64 + lane, lane);
    }
  }

  // refine: exact f32 key for 32 candidates, two rows per pass (lane halves)
  const float* xtB = xt + (size_t)b * NN * CC;
  const float* sqB = sq + (size_t)b * NN;
  #pragma unroll
  for (int r = 0; r < 8; r += 2) {
    const int rl = w * 8 + r;
    const int rowg = n0 + rl + ((lane >= 32) ? 1 : 0);
    const int mhi = __shfl(lm[r + 1], lane & 31);
    const int m = (lane < 32) ? lm[r] : mhi;

    const float4* pr = (const float4*)(xtB + (size_t)rowg * CC);
    const float4* pm = (const float4*)(xtB + (size_t)m * CC);
    float s0 = 0.f, s1 = 0.f, s2 = 0.f, s3 = 0.f;
    #pragma unroll
    for (int i = 0; i < 16; ++i) {
      float4 a = pr[i], c = pm[i];
      s0 += a.x * c.x; s1 += a.y * c.y; s2 += a.z * c.z; s3 += a.w * c.w;
    }
    float ev = sqB[m] - 2.f * ((s0 + s1) + (s2 + s3));  // exact key (row-const dropped)
    int   mv = m;

    for (int k = 0; k < KK; ++k) {
      float v = ev; int mm = mv;
      #pragma unroll
      for (int off = 16; off >= 1; off >>= 1) {   // butterfly min within 32-lane half
        float v2 = __shfl_xor(v, off);
        int  mm2 = __shfl_xor(mm, off);
        bool take = (v2 < v) || (v2 == v && mm2 < mm);
        if (take) { v = v2; mm = mm2; }
      }
      if (ev == v && mv == mm) ev = FMAXV;        // extract winner (m unique)
      if ((lane & 31) == 0)
        knn[((size_t)b * NN + rowg) * KK + k] = mm;
    }
  }
}

// ---------------------------------------------------------------------------
// Kernel UV: u[b,n,o] = dot(W2[o], x_n); v[b,n,o] = dot(W1[o]-W2[o], x_n) + bias[o]
// ---------------------------------------------------------------------------
__global__ __launch_bounds__(256) void kuv(const float* __restrict__ xt,
                                           const float* __restrict__ W,
                                           const float* __restrict__ bias,
                                           float* __restrict__ u,
                                           float* __restrict__ v) {
  __shared__ float sx[64][65];
  const int b = blockIdx.y, n0 = blockIdx.x * 64;
  const int lane = threadIdx.x & 63, w = threadIdx.x >> 6;
  const float4* src = (const float4*)(xt + ((size_t)b * NN + n0) * CC);
  for (int i = threadIdx.x; i < 1024; i += 256) {
    float4 qv = src[i];
    int nl = i >> 4, c4 = (i & 15) << 2;
    sx[nl][c4] = qv.x; sx[nl][c4+1] = qv.y; sx[nl][c4+2] = qv.z; sx[nl][c4+3] = qv.w;
  }
  const int o = lane;
  float w2r[64], wdr[64];
  const float4* W4 = (const float4*)W;
  #pragma unroll
  for (int c4 = 0; c4 < 16; ++c4) {
    float4 q1 = W4[o * 32 + c4];       // W1 part
    float4 q2 = W4[o * 32 + 16 + c4];  // W2 part
    w2r[c4*4]=q2.x; w2r[c4*4+1]=q2.y; w2r[c4*4+2]=q2.z; w2r[c4*4+3]=q2.w;
    wdr[c4*4]=q1.x-q2.x; wdr[c4*4+1]=q1.y-q2.y; wdr[c4*4+2]=q1.z-q2.z; wdr[c4*4+3]=q1.w-q2.w;
  }
  const float bo = bias[o];
  __syncthreads();
  for (int j = 0; j < 16; ++j) {
    int nl = w * 16 + j;
    float du = 0.f, dv = 0.f;
    #pragma unroll
    for (int c = 0; c < 64; ++c) {
      float xv = sx[nl][c];
      du += w2r[c] * xv;
      dv += wdr[c] * xv;
    }
    size_t off = ((size_t)b * NN + n0 + nl) * OO + o;
    u[off] = du;
    v[off] = dv + bo;
  }
}

// ---------------------------------------------------------------------------
// Kernel S: gather stats. Per (b,n): S1/S2 partials per channel; umax/umin.
// ---------------------------------------------------------------------------
__global__ __launch_bounds__(256) void kstats(const float* __restrict__ u,
                                              const float* __restrict__ v,
                                              const int* __restrict__ knn,
                                              float* __restrict__ umax,
                                              float* __restrict__ umin,
                                              float* __restrict__ gS) {
  const int w = threadIdx.x >> 6, lane = threadIdx.x & 63;
  const int gw = blockIdx.x * 4 + w;
  float s1 = 0.f, s2 = 0.f;
  for (int it = 0; it < 16; ++it) {
    int pair = gw * 16 + it;                 // = b*N + n
    const int* ip = knn + (size_t)pair * KK;
    float vv = v[(size_t)pair * OO + lane];
    size_t ubase = ((size_t)(pair >> 12)) * NN * OO;
    float mx = -FMAXV, mn = FMAXV;
    #pragma unroll
    for (int k = 0; k < KK; ++k) {
      int id = ip[k];
      float uu = u[ubase + (size_t)id * OO + lane];
      float y = vv + uu;
      s1 += y; s2 += y * y;
      mx = fmaxf(mx, uu); mn = fminf(mn, uu);
    }
    umax[(size_t)pair * OO + lane] = mx;
    umin[(size_t)pair * OO + lane] = mn;
  }
  __shared__ float r1[4][64], r2[4][64];
  r1[w][lane] = s1; r2[w][lane] = s2;
  __syncthreads();
  if (w == 0) {
    float a = r1[0][lane] + r1[1][lane] + r1[2][lane] + r1[3][lane];
    float c = r2[0][lane] + r2[1][lane] + r2[2][lane] + r2[3][lane];
    atomicAdd(&gS[lane], a);
    atomicAdd(&gS[64 + lane], c);
  }
}

// ---------------------------------------------------------------------------
// Kernel O: normalize, affine, relu, max over k (via umax/umin), transposed store
// ---------------------------------------------------------------------------
__global__ __launch_bounds__(256) void kout(const float* __restrict__ v,
                                            const float* __restrict__ umax,
                                            const float* __restrict__ umin,
                                            const float* __restrict__ gS,
                                            const float* __restrict__ gamma,
                                            const float* __restrict__ beta,
                                            float* __restrict__ out) {
  __shared__ float sA[64], sB[64];
  __shared__ float zt[64][65];
  const int b = blockIdx.y, n0 = blockIdx.x * 64;
  const int lane = threadIdx.x & 63, w = threadIdx.x >> 6;
  if (threadIdx.x < 64) {
    const float cnt = (float)BB * NN * KK;
    float m  = gS[lane] / cnt;
    float var = gS[64 + lane] / cnt - m * m;
    float A = gamma[lane] * rsqrtf(var + 1e-5f);
    sA[lane] = A;
    sB[lane] = beta[lane] - A * m;
  }
  __syncthreads();
  for (int j = 0; j < 16; ++j) {
    int nl = w * 16 + j;
    size_t off = ((size_t)b * NN + n0 + nl) * OO + lane;
    float A = sA[lane];
    float c0 = A * v[off] + sB[lane];
    float z = c0 + A * ((A > 0.f) ? umax[off] : umin[off]);
    zt[nl][lane] = fmaxf(z, 0.f);
  }
  __syncthreads();
  for (int j = 0; j < 16; ++j) {
    int o = w * 16 + j;
    out[((size_t)b * OO + o) * NN + n0 + lane] = zt[lane][o];
  }
}

// ---------------------------------------------------------------------------
extern "C" void kernel_launch(void* const* d_in, const int* in_sizes, int n_in,
                              void* d_out, int out_size, void* d_ws, size_t ws_size,
                              hipStream_t stream) {
  const float* x     = (const float*)d_in[0];
  const float* W     = (const float*)d_in[1];
  const float* bias  = (const float*)d_in[2];
  const float* gamma = (const float*)d_in[3];
  const float* beta  = (const float*)d_in[4];
  float* out = (float*)d_out;

  float* xt  = (float*)d_ws;                    // 2,097,152 f
  float* sq  = xt  + (size_t)BB*NN*CC;          //    32,768 f
  float* u   = sq  + (size_t)BB*NN;             // 2,097,152 f
  float* v   = u   + (size_t)BB*NN*OO;          // 2,097,152 f
  float* umx = v   + (size_t)BB*NN*OO;          // 2,097,152 f
  float* umn = umx + (size_t)BB*NN*OO;          // 2,097,152 f
  float* gS  = umn + (size_t)BB*NN*OO;          //       128 f
  int*   knn = (int*)(gS + 128);                //   655,360 i
  unsigned short* xb = (unsigned short*)(knn + (size_t)BB*NN*KK); // 2,097,152 bf16

  hipMemsetAsync(gS, 0, 128 * sizeof(float), stream);
  ktrans<<<dim3(NN/64, BB), 256, 0, stream>>>(x, xt, xb, sq);
  kuv   <<<dim3(NN/64, BB), 256, 0, stream>>>(xt, W, bias, u, v);
  kknn2 <<<dim3(NN/32, BB), 256, 0, stream>>>(xb, xt, sq, knn);
  kstats<<<dim3(512),       256, 0, stream>>>(u, v, knn, umx, umn, gS);
  kout  <<<dim3(NN/64, BB), 256, 0, stream>>>(v, umx, umn, gS, gamma, beta, out);
}

// Round 3
// 524.744 us; speedup vs baseline: 5.0740x; 5.0740x over previous
//
#include <hip/hip_runtime.h>
#include <hip/hip_bf16.h>

#define BB 8
#define CC 64
#define NN 4096
#define KK 20
#define OO 64
#define FMAXV 3.402823466e38f

typedef __attribute__((ext_vector_type(8))) short short8;   // 8 bf16 = 4 VGPRs (MFMA A/B frag)
typedef __attribute__((ext_vector_type(4))) float f32x4;    // MFMA C/D frag

// ---------------------------------------------------------------------------
// Kernel T: transpose x (B,C,N) -> xt (B,N,C) f32 + xb (B,N,C) bf16; sq[n]=sum x^2
// ---------------------------------------------------------------------------
__global__ __launch_bounds__(256) void ktrans(const float* __restrict__ x,
                                              float* __restrict__ xt,
                                              unsigned short* __restrict__ xb,
                                              float* __restrict__ sq) {
  __shared__ float tile[64][65];
  const int b = blockIdx.y, n0 = blockIdx.x * 64;
  const int lane = threadIdx.x & 63, grp = threadIdx.x >> 6;
  #pragma unroll
  for (int j = 0; j < 16; ++j) {
    int c = grp + j * 4;
    tile[c][lane] = x[((size_t)b * CC + c) * NN + n0 + lane];
  }
  __syncthreads();
  #pragma unroll
  for (int j = 0; j < 16; ++j) {
    int n = grp + j * 4;
    float vv = tile[lane][n];
    size_t off = ((size_t)b * NN + n0 + n) * CC + lane;
    xt[off] = vv;
    unsigned int u = __builtin_bit_cast(unsigned int, vv);
    xb[off] = (unsigned short)((u + 0x7FFFu + ((u >> 16) & 1u)) >> 16);  // RNE bf16
  }
  if (threadIdx.x < 64) {
    float s = 0.f;
    #pragma unroll
    for (int c = 0; c < 64; ++c) { float vv = tile[c][lane]; s += vv * vv; }
    sq[(size_t)b * NN + lane + n0] = s;
  }
}

// ---------------------------------------------------------------------------
// helpers for kknn3
// ---------------------------------------------------------------------------
__device__ __forceinline__ int lanes_below(unsigned long long m) {
  unsigned lo = (unsigned)m, hi = (unsigned)(m >> 32);
  int c = __builtin_amdgcn_mbcnt_lo(lo, 0);
  return (int)__builtin_amdgcn_mbcnt_hi(hi, (unsigned)c);
}

// monotone float->uint, truncate to 20 bits, pack 12-bit index in low bits
__device__ __forceinline__ unsigned packkey(float d, int m) {
  unsigned u = __builtin_bit_cast(unsigned, d);
  u ^= ((int)u < 0) ? 0xFFFFFFFFu : 0x80000000u;
  return (u & 0xFFFFF000u) | (unsigned)m;
}

// full 64-element bitonic sort (ascending), 1 element per lane, 21 stages
__device__ __forceinline__ unsigned bitonic64(unsigned v, int lane) {
  #pragma unroll
  for (int k = 2; k <= 64; k <<= 1) {
    #pragma unroll
    for (int j = k >> 1; j >= 1; j >>= 1) {
      unsigned o = (unsigned)__shfl_xor((int)v, j);
      bool up    = ((lane & k) == 0);
      bool lower = ((lane & j) == 0);
      unsigned mn = (v < o) ? v : o;
      unsigned mx = (v < o) ? o : v;
      v = (up == lower) ? mn : mx;
    }
  }
  return v;
}

// ---------------------------------------------------------------------------
// Kernel KNN3: bf16-MFMA gram + ballot-append/bitonic-merge top-32 + exact
// f32 refine -> top-20. Block: 32 rows, 4 waves; wave w owns rows w*8..w*8+7.
// ---------------------------------------------------------------------------
__global__ __launch_bounds__(256) void kknn3(const unsigned short* __restrict__ xb,
                                             const float* __restrict__ xt,
                                             const float* __restrict__ sq,
                                             int* __restrict__ knn) {
  __shared__ float sd[32][130];          // 2-way bank alias only (free)
  __shared__ float ssq[128];
  __shared__ unsigned sbuf[32][256];     // per-row candidate ring (outstanding <= 159)
  const int b = blockIdx.y;
  const int n0 = blockIdx.x * 32;
  const int lane = threadIdx.x & 63, w = threadIdx.x >> 6;
  const int l15 = lane & 15, q = lane >> 4;

  const unsigned short* xbB = xb + (size_t)b * NN * CC;

  // A frags (whole block): A[m = l15][k = q*8 + j]
  short8 afr[2][2];
  #pragma unroll
  for (int rt = 0; rt < 2; ++rt)
    #pragma unroll
    for (int ks = 0; ks < 2; ++ks) {
      const unsigned short* p = xbB + (size_t)(n0 + rt * 16 + l15) * CC + ks * 32 + q * 8;
      afr[rt][ks] = __builtin_bit_cast(short8, *(const int4*)p);
    }

  // per-row selection state (r-loop fully unrolled -> registers)
  unsigned listv[8], tau[8];
  int cnt[8], done[8];
  #pragma unroll
  for (int r = 0; r < 8; ++r) { listv[r] = 0xFFFFFFFFu; tau[r] = 0xFFFFFFFFu; cnt[r] = 0; done[r] = 0; }

  for (int t = 0; t < NN / 128; ++t) {
    const int c0 = t * 128;
    if (threadIdx.x < 128) ssq[threadIdx.x] = sq[(size_t)b * NN + c0 + threadIdx.x];

    short8 bfr[2][2];
    #pragma unroll
    for (int ct = 0; ct < 2; ++ct)
      #pragma unroll
      for (int ks = 0; ks < 2; ++ks) {
        const unsigned short* p = xbB + (size_t)(c0 + w * 32 + ct * 16 + l15) * CC + ks * 32 + q * 8;
        bfr[ct][ks] = __builtin_bit_cast(short8, *(const int4*)p);
      }
    f32x4 acc[2][2];
    #pragma unroll
    for (int rt = 0; rt < 2; ++rt)
      #pragma unroll
      for (int ct = 0; ct < 2; ++ct) {
        acc[rt][ct] = (f32x4){0.f, 0.f, 0.f, 0.f};
        acc[rt][ct] = __builtin_amdgcn_mfma_f32_16x16x32_bf16(afr[rt][0], bfr[ct][0], acc[rt][ct], 0, 0, 0);
        acc[rt][ct] = __builtin_amdgcn_mfma_f32_16x16x32_bf16(afr[rt][1], bfr[ct][1], acc[rt][ct], 0, 0, 0);
      }

    __syncthreads();   // ssq staged; previous scan done reading sd
    #pragma unroll
    for (int rt = 0; rt < 2; ++rt)
      #pragma unroll
      for (int ct = 0; ct < 2; ++ct) {
        const int cl = w * 32 + ct * 16 + l15;
        #pragma unroll
        for (int j = 0; j < 4; ++j) {
          const int rl = rt * 16 + q * 4 + j;
          float d = ssq[cl] - 2.f * acc[rt][ct][j];
          if (c0 + cl == n0 + rl) d = FMAXV;        // exclude self
          sd[rl][cl] = d;
        }
      }
    __syncthreads();   // sd visible

    // scan: wave w owns rows w*8..w*8+7; 2 candidates/lane via b64 read
    #pragma unroll
    for (int r = 0; r < 8; ++r) {
      const int rl = w * 8 + r;
      float2 dd = *(const float2*)&sd[rl][2 * lane];
      unsigned k0 = packkey(dd.x, c0 + 2 * lane);
      unsigned k1 = packkey(dd.y, c0 + 2 * lane + 1);
      unsigned long long b0 = __ballot(k0 < tau[r]);
      if (k0 < tau[r]) sbuf[rl][(cnt[r] + lanes_below(b0)) & 255] = k0;
      cnt[r] += __popcll(b0);
      unsigned long long b1 = __ballot(k1 < tau[r]);
      if (k1 < tau[r]) sbuf[rl][(cnt[r] + lanes_below(b1)) & 255] = k1;
      cnt[r] += __popcll(b1);
      while (cnt[r] - done[r] >= 32) {
        unsigned chunk = sbuf[rl][(done[r] + (lane & 31)) & 255];
        unsigned v = (lane < 32) ? listv[r] : chunk;
        v = bitonic64(v, lane);
        listv[r] = v;                  // lanes 0..31 = exact top-32 so far (asc)
        tau[r] = (unsigned)__shfl((int)v, 31);
        done[r] += 32;
      }
    }
  }

  // flush leftovers (< 32 outstanding)
  #pragma unroll
  for (int r = 0; r < 8; ++r) {
    const int rl = w * 8 + r;
    int rem = cnt[r] - done[r];
    if (rem > 0) {
      unsigned chunk = ((lane & 31) < rem) ? sbuf[rl][(done[r] + (lane & 31)) & 255] : 0xFFFFFFFFu;
      unsigned v = (lane < 32) ? listv[r] : chunk;
      v = bitonic64(v, lane);
      listv[r] = v;
    }
  }

  // refine: exact f32 key for the 32 candidates, two rows per pass (lane halves)
  const float* xtB = xt + (size_t)b * NN * CC;
  const float* sqB = sq + (size_t)b * NN;
  #pragma unroll
  for (int r = 0; r < 8; r += 2) {
    const int rl = w * 8 + r;
    const int rowg = n0 + rl + ((lane >= 32) ? 1 : 0);
    const unsigned khi = (unsigned)__shfl((int)listv[r + 1], lane & 31);
    const int m = (int)(((lane < 32) ? listv[r] : khi) & 0xFFFu);

    const float4* pr = (const float4*)(xtB + (size_t)rowg * CC);
    const float4* pm = (const float4*)(xtB + (size_t)m * CC);
    float s0 = 0.f, s1 = 0.f, s2 = 0.f, s3 = 0.f;
    #pragma unroll
    for (int i = 0; i < 16; ++i) {
      float4 a = pr[i], c = pm[i];
      s0 += a.x * c.x; s1 += a.y * c.y; s2 += a.z * c.z; s3 += a.w * c.w;
    }
    float ev = sqB[m] - 2.f * ((s0 + s1) + (s2 + s3));  // exact key (row-const dropped)
    int   mv = m;

    for (int k = 0; k < KK; ++k) {
      float v = ev; int mm = mv;
      #pragma unroll
      for (int off = 16; off >= 1; off >>= 1) {   // butterfly min within 32-lane half
        float v2 = __shfl_xor(v, off);
        int  mm2 = __shfl_xor(mm, off);
        bool take = (v2 < v) || (v2 == v && mm2 < mm);
        if (take) { v = v2; mm = mm2; }
      }
      if (ev == v && mv == mm) ev = FMAXV;        // extract winner (m unique)
      if ((lane & 31) == 0)
        knn[((size_t)b * NN + rowg) * KK + k] = mm;
    }
  }
}

// ---------------------------------------------------------------------------
// Kernel UV: u[b,n,o] = dot(W2[o], x_n); v[b,n,o] = dot(W1[o]-W2[o], x_n) + bias[o]
// ---------------------------------------------------------------------------
__global__ __launch_bounds__(256) void kuv(const float* __restrict__ xt,
                                           const float* __restrict__ W,
                                           const float* __restrict__ bias,
                                           float* __restrict__ u,
                                           float* __restrict__ v) {
  __shared__ float sx[64][65];
  const int b = blockIdx.y, n0 = blockIdx.x * 64;
  const int lane = threadIdx.x & 63, w = threadIdx.x >> 6;
  const float4* src = (const float4*)(xt + ((size_t)b * NN + n0) * CC);
  for (int i = threadIdx.x; i < 1024; i += 256) {
    float4 qv = src[i];
    int nl = i >> 4, c4 = (i & 15) << 2;
    sx[nl][c4] = qv.x; sx[nl][c4+1] = qv.y; sx[nl][c4+2] = qv.z; sx[nl][c4+3] = qv.w;
  }
  const int o = lane;
  float w2r[64], wdr[64];
  const float4* W4 = (const float4*)W;
  #pragma unroll
  for (int c4 = 0; c4 < 16; ++c4) {
    float4 q1 = W4[o * 32 + c4];       // W1 part
    float4 q2 = W4[o * 32 + 16 + c4];  // W2 part
    w2r[c4*4]=q2.x; w2r[c4*4+1]=q2.y; w2r[c4*4+2]=q2.z; w2r[c4*4+3]=q2.w;
    wdr[c4*4]=q1.x-q2.x; wdr[c4*4+1]=q1.y-q2.y; wdr[c4*4+2]=q1.z-q2.z; wdr[c4*4+3]=q1.w-q2.w;
  }
  const float bo = bias[o];
  __syncthreads();
  for (int j = 0; j < 16; ++j) {
    int nl = w * 16 + j;
    float du = 0.f, dv = 0.f;
    #pragma unroll
    for (int c = 0; c < 64; ++c) {
      float xv = sx[nl][c];
      du += w2r[c] * xv;
      dv += wdr[c] * xv;
    }
    size_t off = ((size_t)b * NN + n0 + nl) * OO + o;
    u[off] = du;
    v[off] = dv + bo;
  }
}

// ---------------------------------------------------------------------------
// Kernel S: gather stats. Per (b,n): S1/S2 partials per channel; umax/umin.
// ---------------------------------------------------------------------------
__global__ __launch_bounds__(256) void kstats(const float* __restrict__ u,
                                              const float* __restrict__ v,
                                              const int* __restrict__ knn,
                                              float* __restrict__ umax,
                                              float* __restrict__ umin,
                                              float* __restrict__ gS) {
  const int w = threadIdx.x >> 6, lane = threadIdx.x & 63;
  const int gw = blockIdx.x * 4 + w;
  float s1 = 0.f, s2 = 0.f;
  for (int it = 0; it < 16; ++it) {
    int pair = gw * 16 + it;                 // = b*N + n
    const int* ip = knn + (size_t)pair * KK;
    float vv = v[(size_t)pair * OO + lane];
    size_t ubase = ((size_t)(pair >> 12)) * NN * OO;
    float mx = -FMAXV, mn = FMAXV;
    #pragma unroll
    for (int k = 0; k < KK; ++k) {
      int id = ip[k];
      float uu = u[ubase + (size_t)id * OO + lane];
      float y = vv + uu;
      s1 += y; s2 += y * y;
      mx = fmaxf(mx, uu); mn = fminf(mn, uu);
    }
    umax[(size_t)pair * OO + lane] = mx;
    umin[(size_t)pair * OO + lane] = mn;
  }
  __shared__ float r1[4][64], r2[4][64];
  r1[w][lane] = s1; r2[w][lane] = s2;
  __syncthreads();
  if (w == 0) {
    float a = r1[0][lane] + r1[1][lane] + r1[2][lane] + r1[3][lane];
    float c = r2[0][lane] + r2[1][lane] + r2[2][lane] + r2[3][lane];
    atomicAdd(&gS[lane], a);
    atomicAdd(&gS[64 + lane], c);
  }
}

// ---------------------------------------------------------------------------
// Kernel O: normalize, affine, relu, max over k (via umax/umin), transposed store
// ---------------------------------------------------------------------------
__global__ __launch_bounds__(256) void kout(const float* __restrict__ v,
                                            const float* __restrict__ umax,
                                            const float* __restrict__ umin,
                                            const float* __restrict__ gS,
                                            const float* __restrict__ gamma,
                                            const float* __restrict__ beta,
                                            float* __restrict__ out) {
  __shared__ float sA[64], sB[64];
  __shared__ float zt[64][65];
  const int b = blockIdx.y, n0 = blockIdx.x * 64;
  const int lane = threadIdx.x & 63, w = threadIdx.x >> 6;
  if (threadIdx.x < 64) {
    const float cnt = (float)BB * NN * KK;
    float m  = gS[lane] / cnt;
    float var = gS[64 + lane] / cnt - m * m;
    float A = gamma[lane] * rsqrtf(var + 1e-5f);
    sA[lane] = A;
    sB[lane] = beta[lane] - A * m;
  }
  __syncthreads();
  for (int j = 0; j < 16; ++j) {
    int nl = w * 16 + j;
    size_t off = ((size_t)b * NN + n0 + nl) * OO + lane;
    float A = sA[lane];
    float c0 = A * v[off] + sB[lane];
    float z = c0 + A * ((A > 0.f) ? umax[off] : umin[off]);
    zt[nl][lane] = fmaxf(z, 0.f);
  }
  __syncthreads();
  for (int j = 0; j < 16; ++j) {
    int o = w * 16 + j;
    out[((size_t)b * OO + o) * NN + n0 + lane] = zt[lane][o];
  }
}

// ---------------------------------------------------------------------------
extern "C" void kernel_launch(void* const* d_in, const int* in_sizes, int n_in,
                              void* d_out, int out_size, void* d_ws, size_t ws_size,
                              hipStream_t stream) {
  const float* x     = (const float*)d_in[0];
  const float* W     = (const float*)d_in[1];
  const float* bias  = (const float*)d_in[2];
  const float* gamma = (const float*)d_in[3];
  const float* beta  = (const float*)d_in[4];
  float* out = (float*)d_out;

  float* xt  = (float*)d_ws;                    // 2,097,152 f
  float* sq  = xt  + (size_t)BB*NN*CC;          //    32,768 f
  float* u   = sq  + (size_t)BB*NN;             // 2,097,152 f
  float* v   = u   + (size_t)BB*NN*OO;          // 2,097,152 f
  float* umx = v   + (size_t)BB*NN*OO;          // 2,097,152 f
  float* umn = umx + (size_t)BB*NN*OO;          // 2,097,152 f
  float* gS  = umn + (size_t)BB*NN*OO;          //       128 f
  int*   knn = (int*)(gS + 128);                //   655,360 i
  unsigned short* xb = (unsigned short*)(knn + (size_t)BB*NN*KK); // 2,097,152 bf16

  hipMemsetAsync(gS, 0, 128 * sizeof(float), stream);
  ktrans<<<dim3(NN/64, BB), 256, 0, stream>>>(x, xt, xb, sq);
  kuv   <<<dim3(NN/64, BB), 256, 0, stream>>>(xt, W, bias, u, v);
  kknn3 <<<dim3(NN/32, BB), 256, 0, stream>>>(xb, xt, sq, knn);
  kstats<<<dim3(512),       256, 0, stream>>>(u, v, knn, umx, umn, gS);
  kout  <<<dim3(NN/64, BB), 256, 0, stream>>>(v, umx, umn, gS, gamma, beta, out);
}

// Round 4
// 507.821 us; speedup vs baseline: 5.2431x; 1.0333x over previous
//
#include <hip/hip_runtime.h>
#include <hip/hip_bf16.h>

#define BB 8
#define CC 64
#define NN 4096
#define KK 20
#define OO 64
#define FMAXV 3.402823466e38f

typedef __attribute__((ext_vector_type(8))) short short8;   // 8 bf16 = 4 VGPRs (MFMA A/B frag)
typedef __attribute__((ext_vector_type(4))) float f32x4;    // MFMA C/D frag

// ---------------------------------------------------------------------------
// Kernel T: transpose x (B,C,N) -> xt (B,N,C) f32 + xb (B,N,C) bf16; sq[n]=sum x^2
// ---------------------------------------------------------------------------
__global__ __launch_bounds__(256) void ktrans(const float* __restrict__ x,
                                              float* __restrict__ xt,
                                              unsigned short* __restrict__ xb,
                                              float* __restrict__ sq) {
  __shared__ float tile[64][65];
  const int b = blockIdx.y, n0 = blockIdx.x * 64;
  const int lane = threadIdx.x & 63, grp = threadIdx.x >> 6;
  #pragma unroll
  for (int j = 0; j < 16; ++j) {
    int c = grp + j * 4;
    tile[c][lane] = x[((size_t)b * CC + c) * NN + n0 + lane];
  }
  __syncthreads();
  #pragma unroll
  for (int j = 0; j < 16; ++j) {
    int n = grp + j * 4;
    float vv = tile[lane][n];
    size_t off = ((size_t)b * NN + n0 + n) * CC + lane;
    xt[off] = vv;
    unsigned int u = __builtin_bit_cast(unsigned int, vv);
    xb[off] = (unsigned short)((u + 0x7FFFu + ((u >> 16) & 1u)) >> 16);  // RNE bf16
  }
  if (threadIdx.x < 64) {
    float s = 0.f;
    #pragma unroll
    for (int c = 0; c < 64; ++c) { float vv = tile[c][lane]; s += vv * vv; }
    sq[(size_t)b * NN + lane + n0] = s;
  }
}

// ---------------------------------------------------------------------------
// helpers for kknn4
// ---------------------------------------------------------------------------
__device__ __forceinline__ int lanes_below(unsigned long long m) {
  unsigned lo = (unsigned)m, hi = (unsigned)(m >> 32);
  int c = __builtin_amdgcn_mbcnt_lo(lo, 0);
  return (int)__builtin_amdgcn_mbcnt_hi(hi, (unsigned)c);
}

// monotone float->uint, truncate to 20 bits, pack 12-bit index in low bits
__device__ __forceinline__ unsigned packkey(float d, int m) {
  unsigned u = __builtin_bit_cast(unsigned, d);
  u ^= ((int)u < 0) ? 0xFFFFFFFFu : 0x80000000u;
  return (u & 0xFFFFF000u) | (unsigned)m;
}

// full 64-element bitonic sort (ascending), 1 element per lane, 21 stages
__device__ __forceinline__ unsigned bitonic64(unsigned v, int lane) {
  #pragma unroll
  for (int k = 2; k <= 64; k <<= 1) {
    #pragma unroll
    for (int j = k >> 1; j >= 1; j >>= 1) {
      unsigned o = (unsigned)__shfl_xor((int)v, j);
      bool up    = ((lane & k) == 0);
      bool lower = ((lane & j) == 0);
      unsigned mn = (v < o) ? v : o;
      unsigned mx = (v < o) ? o : v;
      v = (up == lower) ? mn : mx;
    }
  }
  return v;
}

// ---------------------------------------------------------------------------
// Kernel KNN4: bf16-MFMA gram + ballot-append/bitonic-merge top-32 + exact
// f32 refine -> top-20. Block: 32 rows, 4 waves; wave w owns rows w*8..w*8+7.
// Pipelined: B-frags/sq prefetched during scan; MFMA runs pre-barrier so it
// overlaps other waves' scan. LDS 33 KB -> 4 blocks/CU.
// ---------------------------------------------------------------------------
__global__ __launch_bounds__(256) void kknn4(const unsigned short* __restrict__ xb,
                                             const float* __restrict__ xt,
                                             const float* __restrict__ sq,
                                             int* __restrict__ knn) {
  __shared__ float sd[32][130];          // 16.6 KB; 2-way bank alias only (free)
  __shared__ unsigned sbuf[32][128];     // 16 KB; per-row ring (outstanding <= 95)
  const int b = blockIdx.y;
  const int n0 = blockIdx.x * 32;
  const int lane = threadIdx.x & 63, w = threadIdx.x >> 6;
  const int l15 = lane & 15, q = lane >> 4;

  const unsigned short* xbB = xb + (size_t)b * NN * CC;
  const float* sqB = sq + (size_t)b * NN;

  // A frags (whole block): A[m = l15][k = q*8 + j]
  short8 afr[2][2];
  #pragma unroll
  for (int rt = 0; rt < 2; ++rt)
    #pragma unroll
    for (int ks = 0; ks < 2; ++ks) {
      const unsigned short* p = xbB + (size_t)(n0 + rt * 16 + l15) * CC + ks * 32 + q * 8;
      afr[rt][ks] = __builtin_bit_cast(short8, *(const int4*)p);
    }

  // per-row selection state (r-loop fully unrolled -> registers)
  unsigned listv[8], tau[8];
  int cnt[8], done[8];
  #pragma unroll
  for (int r = 0; r < 8; ++r) { listv[r] = 0xFFFFFFFFu; tau[r] = 0xFFFFFFFFu; cnt[r] = 0; done[r] = 0; }

  // prologue: prefetch tile 0 B-frags + sq cols
  short8 bfr[2][2];
  float sqv[2];
  #pragma unroll
  for (int ct = 0; ct < 2; ++ct) {
    #pragma unroll
    for (int ks = 0; ks < 2; ++ks) {
      const unsigned short* p = xbB + (size_t)(w * 32 + ct * 16 + l15) * CC + ks * 32 + q * 8;
      bfr[ct][ks] = __builtin_bit_cast(short8, *(const int4*)p);
    }
    sqv[ct] = sqB[w * 32 + ct * 16 + l15];
  }

  for (int t = 0; t < NN / 128; ++t) {
    const int c0 = t * 128;

    // MFMA for tile t (from prefetched frags) — overlaps other waves' scan
    f32x4 acc[2][2];
    #pragma unroll
    for (int rt = 0; rt < 2; ++rt)
      #pragma unroll
      for (int ct = 0; ct < 2; ++ct) {
        acc[rt][ct] = (f32x4){0.f, 0.f, 0.f, 0.f};
        acc[rt][ct] = __builtin_amdgcn_mfma_f32_16x16x32_bf16(afr[rt][0], bfr[ct][0], acc[rt][ct], 0, 0, 0);
        acc[rt][ct] = __builtin_amdgcn_mfma_f32_16x16x32_bf16(afr[rt][1], bfr[ct][1], acc[rt][ct], 0, 0, 0);
      }

    __syncthreads();   // previous scan done reading sd
    #pragma unroll
    for (int rt = 0; rt < 2; ++rt)
      #pragma unroll
      for (int ct = 0; ct < 2; ++ct) {
        const int cl = w * 32 + ct * 16 + l15;
        #pragma unroll
        for (int j = 0; j < 4; ++j) {
          const int rl = rt * 16 + q * 4 + j;
          float d = sqv[ct] - 2.f * acc[rt][ct][j];
          if (c0 + cl == n0 + rl) d = FMAXV;        // exclude self
          sd[rl][cl] = d;
        }
      }
    __syncthreads();   // sd visible

    // prefetch tile t+1 (VMEM latency hidden by the scan below)
    if (t < NN / 128 - 1) {
      const int c1 = c0 + 128;
      #pragma unroll
      for (int ct = 0; ct < 2; ++ct) {
        #pragma unroll
        for (int ks = 0; ks < 2; ++ks) {
          const unsigned short* p = xbB + (size_t)(c1 + w * 32 + ct * 16 + l15) * CC + ks * 32 + q * 8;
          bfr[ct][ks] = __builtin_bit_cast(short8, *(const int4*)p);
        }
        sqv[ct] = sqB[c1 + w * 32 + ct * 16 + l15];
      }
    }

    // scan: wave w owns rows w*8..w*8+7; 2 candidates/lane; merge-check per half
    #pragma unroll
    for (int r = 0; r < 8; ++r) {
      const int rl = w * 8 + r;
      float2 dd = *(const float2*)&sd[rl][2 * lane];
      unsigned k0 = packkey(dd.x, c0 + 2 * lane);
      unsigned k1 = packkey(dd.y, c0 + 2 * lane + 1);
      unsigned long long b0 = __ballot(k0 < tau[r]);
      if (k0 < tau[r]) sbuf[rl][(cnt[r] + lanes_below(b0)) & 127] = k0;
      cnt[r] += __popcll(b0);
      while (cnt[r] - done[r] >= 32) {
        unsigned chunk = sbuf[rl][(done[r] + (lane & 31)) & 127];
        unsigned v = (lane < 32) ? listv[r] : chunk;
        v = bitonic64(v, lane);
        listv[r] = v;                  // lanes 0..31 = exact top-32 so far (asc)
        tau[r] = (unsigned)__shfl((int)v, 31);
        done[r] += 32;
      }
      unsigned long long b1 = __ballot(k1 < tau[r]);
      if (k1 < tau[r]) sbuf[rl][(cnt[r] + lanes_below(b1)) & 127] = k1;
      cnt[r] += __popcll(b1);
      while (cnt[r] - done[r] >= 32) {
        unsigned chunk = sbuf[rl][(done[r] + (lane & 31)) & 127];
        unsigned v = (lane < 32) ? listv[r] : chunk;
        v = bitonic64(v, lane);
        listv[r] = v;
        tau[r] = (unsigned)__shfl((int)v, 31);
        done[r] += 32;
      }
    }
  }

  // flush leftovers (< 32 outstanding)
  #pragma unroll
  for (int r = 0; r < 8; ++r) {
    const int rl = w * 8 + r;
    int rem = cnt[r] - done[r];
    if (rem > 0) {
      unsigned chunk = ((lane & 31) < rem) ? sbuf[rl][(done[r] + (lane & 31)) & 127] : 0xFFFFFFFFu;
      unsigned v = (lane < 32) ? listv[r] : chunk;
      v = bitonic64(v, lane);
      listv[r] = v;
    }
  }

  // refine: exact f32 key for the 32 candidates, two rows per pass (lane halves)
  const float* xtB = xt + (size_t)b * NN * CC;
  #pragma unroll
  for (int r = 0; r < 8; r += 2) {
    const int rl = w * 8 + r;
    const int rowg = n0 + rl + ((lane >= 32) ? 1 : 0);
    const unsigned khi = (unsigned)__shfl((int)listv[r + 1], lane & 31);
    const int m = (int)(((lane < 32) ? listv[r] : khi) & 0xFFFu);

    const float4* pr = (const float4*)(xtB + (size_t)rowg * CC);
    const float4* pm = (const float4*)(xtB + (size_t)m * CC);
    float s0 = 0.f, s1 = 0.f, s2 = 0.f, s3 = 0.f;
    #pragma unroll
    for (int i = 0; i < 16; ++i) {
      float4 a = pr[i], c = pm[i];
      s0 += a.x * c.x; s1 += a.y * c.y; s2 += a.z * c.z; s3 += a.w * c.w;
    }
    float ev = sqB[m] - 2.f * ((s0 + s1) + (s2 + s3));  // exact key (row-const dropped)
    int   mv = m;

    for (int k = 0; k < KK; ++k) {
      float v = ev; int mm = mv;
      #pragma unroll
      for (int off = 16; off >= 1; off >>= 1) {   // butterfly min within 32-lane half
        float v2 = __shfl_xor(v, off);
        int  mm2 = __shfl_xor(mm, off);
        bool take = (v2 < v) || (v2 == v && mm2 < mm);
        if (take) { v = v2; mm = mm2; }
      }
      if (ev == v && mv == mm) ev = FMAXV;        // extract winner (m unique)
      if ((lane & 31) == 0)
        knn[((size_t)b * NN + rowg) * KK + k] = mm;
    }
  }
}

// ---------------------------------------------------------------------------
// Kernel UV: u[b,n,o] = dot(W2[o], x_n); v[b,n,o] = dot(W1[o]-W2[o], x_n) + bias[o]
// ---------------------------------------------------------------------------
__global__ __launch_bounds__(256) void kuv(const float* __restrict__ xt,
                                           const float* __restrict__ W,
                                           const float* __restrict__ bias,
                                           float* __restrict__ u,
                                           float* __restrict__ v) {
  __shared__ float sx[64][65];
  const int b = blockIdx.y, n0 = blockIdx.x * 64;
  const int lane = threadIdx.x & 63, w = threadIdx.x >> 6;
  const float4* src = (const float4*)(xt + ((size_t)b * NN + n0) * CC);
  for (int i = threadIdx.x; i < 1024; i += 256) {
    float4 qv = src[i];
    int nl = i >> 4, c4 = (i & 15) << 2;
    sx[nl][c4] = qv.x; sx[nl][c4+1] = qv.y; sx[nl][c4+2] = qv.z; sx[nl][c4+3] = qv.w;
  }
  const int o = lane;
  float w2r[64], wdr[64];
  const float4* W4 = (const float4*)W;
  #pragma unroll
  for (int c4 = 0; c4 < 16; ++c4) {
    float4 q1 = W4[o * 32 + c4];       // W1 part
    float4 q2 = W4[o * 32 + 16 + c4];  // W2 part
    w2r[c4*4]=q2.x; w2r[c4*4+1]=q2.y; w2r[c4*4+2]=q2.z; w2r[c4*4+3]=q2.w;
    wdr[c4*4]=q1.x-q2.x; wdr[c4*4+1]=q1.y-q2.y; wdr[c4*4+2]=q1.z-q2.z; wdr[c4*4+3]=q1.w-q2.w;
  }
  const float bo = bias[o];
  __syncthreads();
  for (int j = 0; j < 16; ++j) {
    int nl = w * 16 + j;
    float du = 0.f, dv = 0.f;
    #pragma unroll
    for (int c = 0; c < 64; ++c) {
      float xv = sx[nl][c];
      du += w2r[c] * xv;
      dv += wdr[c] * xv;
    }
    size_t off = ((size_t)b * NN + n0 + nl) * OO + o;
    u[off] = du;
    v[off] = dv + bo;
  }
}

// ---------------------------------------------------------------------------
// Kernel S: gather stats. Per (b,n): S1/S2 partials per channel; umax/umin.
// ---------------------------------------------------------------------------
__global__ __launch_bounds__(256) void kstats(const float* __restrict__ u,
                                              const float* __restrict__ v,
                                              const int* __restrict__ knn,
                                              float* __restrict__ umax,
                                              float* __restrict__ umin,
                                              float* __restrict__ gS) {
  const int w = threadIdx.x >> 6, lane = threadIdx.x & 63;
  const int gw = blockIdx.x * 4 + w;
  float s1 = 0.f, s2 = 0.f;
  for (int it = 0; it < 16; ++it) {
    int pair = gw * 16 + it;                 // = b*N + n
    const int* ip = knn + (size_t)pair * KK;
    float vv = v[(size_t)pair * OO + lane];
    size_t ubase = ((size_t)(pair >> 12)) * NN * OO;
    float mx = -FMAXV, mn = FMAXV;
    #pragma unroll
    for (int k = 0; k < KK; ++k) {
      int id = ip[k];
      float uu = u[ubase + (size_t)id * OO + lane];
      float y = vv + uu;
      s1 += y; s2 += y * y;
      mx = fmaxf(mx, uu); mn = fminf(mn, uu);
    }
    umax[(size_t)pair * OO + lane] = mx;
    umin[(size_t)pair * OO + lane] = mn;
  }
  __shared__ float r1[4][64], r2[4][64];
  r1[w][lane] = s1; r2[w][lane] = s2;
  __syncthreads();
  if (w == 0) {
    float a = r1[0][lane] + r1[1][lane] + r1[2][lane] + r1[3][lane];
    float c = r2[0][lane] + r2[1][lane] + r2[2][lane] + r2[3][lane];
    atomicAdd(&gS[lane], a);
    atomicAdd(&gS[64 + lane], c);
  }
}

// ---------------------------------------------------------------------------
// Kernel O: normalize, affine, relu, max over k (via umax/umin), transposed store
// ---------------------------------------------------------------------------
__global__ __launch_bounds__(256) void kout(const float* __restrict__ v,
                                            const float* __restrict__ umax,
                                            const float* __restrict__ umin,
                                            const float* __restrict__ gS,
                                            const float* __restrict__ gamma,
                                            const float* __restrict__ beta,
                                            float* __restrict__ out) {
  __shared__ float sA[64], sB[64];
  __shared__ float zt[64][65];
  const int b = blockIdx.y, n0 = blockIdx.x * 64;
  const int lane = threadIdx.x & 63, w = threadIdx.x >> 6;
  if (threadIdx.x < 64) {
    const float cnt = (float)BB * NN * KK;
    float m  = gS[lane] / cnt;
    float var = gS[64 + lane] / cnt - m * m;
    float A = gamma[lane] * rsqrtf(var + 1e-5f);
    sA[lane] = A;
    sB[lane] = beta[lane] - A * m;
  }
  __syncthreads();
  for (int j = 0; j < 16; ++j) {
    int nl = w * 16 + j;
    size_t off = ((size_t)b * NN + n0 + nl) * OO + lane;
    float A = sA[lane];
    float c0 = A * v[off] + sB[lane];
    float z = c0 + A * ((A > 0.f) ? umax[off] : umin[off]);
    zt[nl][lane] = fmaxf(z, 0.f);
  }
  __syncthreads();
  for (int j = 0; j < 16; ++j) {
    int o = w * 16 + j;
    out[((size_t)b * OO + o) * NN + n0 + lane] = zt[lane][o];
  }
}

// ---------------------------------------------------------------------------
extern "C" void kernel_launch(void* const* d_in, const int* in_sizes, int n_in,
                              void* d_out, int out_size, void* d_ws, size_t ws_size,
                              hipStream_t stream) {
  const float* x     = (const float*)d_in[0];
  const float* W     = (const float*)d_in[1];
  const float* bias  = (const float*)d_in[2];
  const float* gamma = (const float*)d_in[3];
  const float* beta  = (const float*)d_in[4];
  float* out = (float*)d_out;

  float* xt  = (float*)d_ws;                    // 2,097,152 f
  float* sq  = xt  + (size_t)BB*NN*CC;          //    32,768 f
  float* u   = sq  + (size_t)BB*NN;             // 2,097,152 f
  float* v   = u   + (size_t)BB*NN*OO;          // 2,097,152 f
  float* umx = v   + (size_t)BB*NN*OO;          // 2,097,152 f
  float* umn = umx + (size_t)BB*NN*OO;          // 2,097,152 f
  float* gS  = umn + (size_t)BB*NN*OO;          //       128 f
  int*   knn = (int*)(gS + 128);                //   655,360 i
  unsigned short* xb = (unsigned short*)(knn + (size_t)BB*NN*KK); // 2,097,152 bf16

  hipMemsetAsync(gS, 0, 128 * sizeof(float), stream);
  ktrans<<<dim3(NN/64, BB), 256, 0, stream>>>(x, xt, xb, sq);
  kuv   <<<dim3(NN/64, BB), 256, 0, stream>>>(xt, W, bias, u, v);
  kknn4 <<<dim3(NN/32, BB), 256, 0, stream>>>(xb, xt, sq, knn);
  kstats<<<dim3(512),       256, 0, stream>>>(u, v, knn, umx, umn, gS);
  kout  <<<dim3(NN/64, BB), 256, 0, stream>>>(v, umx, umn, gS, gamma, beta, out);
}